// Round 3
// baseline (669.130 us; speedup 1.0000x reference)
//
#include <hip/hip_runtime.h>
#include <hip/hip_bf16.h>
#include <math.h>

// Shapes fixed by the reference
#define TT     365
#define BT     23360      // 64*365
#define NPOS   425

typedef __hip_bfloat16 bf16;

__device__ __forceinline__ float b2f(bf16 v) { return __bfloat162float(v); }
__device__ __forceinline__ bf16  f2b(float v) { return __float2bfloat16(v); }

// ---------------- zero-fill (NO hipMemsetAsync anywhere: pure-kernel stream) ----------------
__global__ __launch_bounds__(256) void zero_kernel(float* __restrict__ p, int n) {
    int i = blockIdx.x * 256 + threadIdx.x;
    if (i < n) p[i] = 0.f;
}

// ---------------- cast x: fp32 -> bf16 ----------------
__global__ __launch_bounds__(256) void cast_kernel(const float* __restrict__ x,
                                                   bf16* __restrict__ xb, int n) {
    int i = blockIdx.x * 256 + threadIdx.x;
    if (i < n) xb[i] = f2b(x[i]);
}

// ---------------- sinusoidal table in f64, cast f32 (matches numpy) ----------------
__global__ __launch_bounds__(256) void postab_kernel(float* __restrict__ tab) {
    int i = blockIdx.x * 256 + threadIdx.x;   // 425*256 exact
    int c = i & 255, p = i >> 8;
    double e = (double)(2 * (c >> 1)) / 256.0;
    double ang = (double)p / pow(1000.0, e);
    tab[i] = (float)((c & 1) ? cos(ang) : sin(ang));
}

// ---------------- GEMM: Y[M,ldY](bf16) = A[M,K](bf16) @ W[N,K]^T + bias(f32); fused BN stats ----
// 64 rows x NCOLS cols per block, 256 threads (16x16 micro-tile, 4 x NCOLS/16 per thread).
template<int NCOLS>
__global__ __launch_bounds__(256) void gemm_kernel(
    const bf16* __restrict__ A, int K,
    const float* __restrict__ W, const float* __restrict__ bias,
    bf16* __restrict__ Y, int ldY,
    float* __restrict__ stats)     // sum at [col0+t], sumsq at [256+col0+t]; may be null
{
    const int t  = threadIdx.x;
    const int tx = t & 15, ty = t >> 4;
    const int row0 = blockIdx.x * 64;
    const int col0 = blockIdx.y * NCOLS;
    constexpr int CPT = NCOLS / 16;
    __shared__ float As[64][17];
    __shared__ float Ws[16][NCOLS + 1];
    __shared__ float red_s[4][NCOLS];
    __shared__ float red_q[4][NCOLS];
    float acc[4][CPT];
#pragma unroll
    for (int rr = 0; rr < 4; ++rr)
#pragma unroll
        for (int cc = 0; cc < CPT; ++cc) acc[rr][cc] = 0.f;
    const float* Wb = W + (size_t)col0 * K;
    for (int k0 = 0; k0 < K; k0 += 16) {
#pragma unroll
        for (int i = 0; i < 4; ++i) {
            int idx = t + i * 256, r = idx >> 4, c = idx & 15, k = k0 + c;
            As[r][c] = (k < K) ? b2f(A[(size_t)(row0 + r) * K + k]) : 0.f;
        }
#pragma unroll
        for (int i = 0; i < CPT; ++i) {
            int idx = t + i * 256, c = idx >> 4, kk = idx & 15, k = k0 + kk;
            Ws[kk][c] = (k < K) ? Wb[(size_t)c * K + k] : 0.f;
        }
        __syncthreads();
#pragma unroll
        for (int kk = 0; kk < 16; ++kk) {
            float a[4];
#pragma unroll
            for (int rr = 0; rr < 4; ++rr) a[rr] = As[ty * 4 + rr][kk];
#pragma unroll
            for (int cc = 0; cc < CPT; ++cc) {
                float w = Ws[kk][cc * 16 + tx];
#pragma unroll
                for (int rr = 0; rr < 4; ++rr) acc[rr][cc] = fmaf(a[rr], w, acc[rr][cc]);
            }
        }
        __syncthreads();
    }
    // epilogue: bias, store bf16, per-thread column partial sums
    float s_cc[CPT], q_cc[CPT];
#pragma unroll
    for (int cc = 0; cc < CPT; ++cc) { s_cc[cc] = 0.f; q_cc[cc] = 0.f; }
#pragma unroll
    for (int rr = 0; rr < 4; ++rr) {
        int row = row0 + ty * 4 + rr;
#pragma unroll
        for (int cc = 0; cc < CPT; ++cc) {
            int col = col0 + cc * 16 + tx;
            float v = acc[rr][cc] + bias[col];
            Y[(size_t)row * ldY + col] = f2b(v);
            s_cc[cc] += v; q_cc[cc] += v * v;
        }
    }
    if (stats) {
        int w = t >> 6;   // wave id; lanes {tx, tx+16, tx+32, tx+48} share a column
#pragma unroll
        for (int cc = 0; cc < CPT; ++cc) {
            float s = s_cc[cc], q = q_cc[cc];
            s += __shfl_xor(s, 16); q += __shfl_xor(q, 16);
            s += __shfl_xor(s, 32); q += __shfl_xor(q, 32);
            if ((t & 63) < 16) { red_s[w][cc * 16 + tx] = s; red_q[w][cc * 16 + tx] = q; }
        }
        __syncthreads();
        if (t < NCOLS) {
            float s = red_s[0][t] + red_s[1][t] + red_s[2][t] + red_s[3][t];
            float q = red_q[0][t] + red_q[1][t] + red_q[2][t] + red_q[3][t];
            atomicAdd(&stats[col0 + t], s);
            atomicAdd(&stats[256 + col0 + t], q);
        }
    }
}

// ---------------- BN (batch stats over BT rows) + ReLU (+ optional positional add) ----------------
__global__ __launch_bounds__(256) void bnrelu_kernel(
    const bf16* __restrict__ Y, int N, const float* __restrict__ stats,
    const float* __restrict__ g, const float* __restrict__ beta,
    bf16* __restrict__ Out,
    const float* __restrict__ tab, const int* __restrict__ pos) {
    int i = blockIdx.x * 256 + threadIdx.x;    // grid sized exactly BT*N/256
    int col = i % N, row = i / N;
    const float invM = 1.f / (float)BT;
    float mu  = stats[col] * invM;
    float var = stats[256 + col] * invM - mu * mu;
    float v = (b2f(Y[i]) - mu) * rsqrtf(var + 1e-5f) * g[col] + beta[col];
    v = fmaxf(v, 0.f);
    if (tab) v += tab[pos[row] * 256 + col];   // N==256 path only
    Out[i] = f2b(v);
}

// ---------------- SE: se[b,f] = sigmoid(relu(pooled@ws1^T)@ws2^T) * pooled ----------------
__global__ __launch_bounds__(256) void se_kernel(const bf16* __restrict__ a3,
                                                 const float* __restrict__ ws1,
                                                 const float* __restrict__ ws2,
                                                 float* __restrict__ se) {
    int b = blockIdx.x, f = threadIdx.x;
    __shared__ float pooled[256];
    __shared__ float hidden[16];
    const bf16* base = a3 + (size_t)b * TT * 256;
    float s = 0.f;
    for (int tt = 0; tt < TT; ++tt) s += b2f(base[(size_t)tt * 256 + f]);
    pooled[f] = s * (1.f / (float)TT);
    __syncthreads();
    if (f < 16) {
        float h = 0.f;
        for (int k = 0; k < 256; ++k) h = fmaf(pooled[k], ws1[f * 256 + k], h);
        hidden[f] = fmaxf(h, 0.f);
    }
    __syncthreads();
    float a = 0.f;
    for (int k = 0; k < 16; ++k) a = fmaf(hidden[k], ws2[f * 16 + k], a);
    a = 1.f / (1.f + expf(-a));
    se[b * 256 + f] = a * pooled[f];
}

__global__ __launch_bounds__(256) void residual_kernel(const bf16* __restrict__ a3,
                                                       const float* __restrict__ se,
                                                       bf16* __restrict__ out) {
    int i = blockIdx.x * 256 + threadIdx.x;    // BT*256/256 blocks exact
    int col = i & 255, row = i >> 8;
    int b = row / TT;
    out[i] = f2b(b2f(a3[i]) + se[b * 256 + col]);
}

// ---------------- ksum[b, h*8+d] = sum_t k[b,t,h*8+d] ----------------
__global__ __launch_bounds__(128) void ksum_kernel(const bf16* __restrict__ k,
                                                   float* __restrict__ ksum) {
    int b = blockIdx.x, f = threadIdx.x;
    const bf16* base = k + (size_t)b * TT * 128;
    float s = 0.f;
    for (int tt = 0; tt < TT; ++tt) s += b2f(base[(size_t)tt * 128 + f]);
    ksum[b * 128 + f] = s;
}

// ---------------- per-(b,h) mean-score softmax over T; one wave each ----------------
__global__ __launch_bounds__(64) void attsm_kernel(const bf16* __restrict__ q,
                                                   const float* __restrict__ ksum,
                                                   float* __restrict__ attw) {
    int bh = blockIdx.x, b = bh >> 4, h = bh & 15;
    int lane = threadIdx.x;
    float kk[8];
#pragma unroll
    for (int d = 0; d < 8; ++d) kk[d] = ksum[b * 128 + h * 8 + d];
    const float scale = 1.f / (sqrtf(8.f) * (float)TT);
    float sv[6];
    float m = -1e30f;
#pragma unroll
    for (int i = 0; i < 6; ++i) {
        int tt = lane + i * 64;
        float v = -1e30f;
        if (tt < TT) {
            const uint4 raw = *(const uint4*)(q + (size_t)(b * TT + tt) * 128 + h * 8);
            float qv[8];
            qv[0] = __uint_as_float(raw.x << 16); qv[1] = __uint_as_float(raw.x & 0xffff0000u);
            qv[2] = __uint_as_float(raw.y << 16); qv[3] = __uint_as_float(raw.y & 0xffff0000u);
            qv[4] = __uint_as_float(raw.z << 16); qv[5] = __uint_as_float(raw.z & 0xffff0000u);
            qv[6] = __uint_as_float(raw.w << 16); qv[7] = __uint_as_float(raw.w & 0xffff0000u);
            float dot = 0.f;
#pragma unroll
            for (int d = 0; d < 8; ++d) dot = fmaf(qv[d], kk[d], dot);
            v = dot * scale;
        }
        sv[i] = v;
        m = fmaxf(m, v);
    }
    for (int off = 32; off > 0; off >>= 1) m = fmaxf(m, __shfl_xor(m, off));
    float sum = 0.f;
#pragma unroll
    for (int i = 0; i < 6; ++i) {
        float e = (sv[i] > -1e29f) ? expf(sv[i] - m) : 0.f;
        sv[i] = e; sum += e;
    }
    for (int off = 32; off > 0; off >>= 1) sum += __shfl_xor(sum, off);
    float inv = 1.f / sum;
#pragma unroll
    for (int i = 0; i < 6; ++i) {
        int tt = lane + i * 64;
        if (tt < TT) attw[(size_t)bh * TT + tt] = sv[i] * inv;
    }
}

// ---------------- y[b,f] = sum_t attw[b, f/16, t] * e[b,t,f] ----------------
__global__ __launch_bounds__(256) void yv_kernel(const bf16* __restrict__ e,
                                                 const float* __restrict__ attw,
                                                 float* __restrict__ yv) {
    int b = blockIdx.x, f = threadIdx.x;
    int h = f >> 4;
    const bf16* base = e + (size_t)b * TT * 256;
    const float* aw = attw + (size_t)(b * 16 + h) * TT;
    float s = 0.f;
    for (int tt = 0; tt < TT; ++tt) s = fmaf(aw[tt], b2f(base[(size_t)tt * 256 + f]), s);
    yv[b * 256 + f] = s;
}

// ---------------- fused tail: 3 BN-linear layers + classifier, one block ----------------
template<int N, int K>
__device__ void tail_layer(const float* __restrict__ X, int ldx,
                           const float* __restrict__ W, const float* __restrict__ bias,
                           const float* __restrict__ g, const float* __restrict__ beta,
                           float* Z, float* scr) {
    const int t = threadIdx.x;
    const int tx = t & 15, ty = t >> 4;
    constexpr int CPT = N / 16;
    float acc[4][CPT];
#pragma unroll
    for (int rr = 0; rr < 4; ++rr)
#pragma unroll
        for (int cc = 0; cc < CPT; ++cc) acc[rr][cc] = 0.f;
    for (int k = 0; k < K; ++k) {
        float a[4];
#pragma unroll
        for (int rr = 0; rr < 4; ++rr) a[rr] = X[(ty * 4 + rr) * ldx + k];
#pragma unroll
        for (int cc = 0; cc < CPT; ++cc) {
            float w = W[(cc * 16 + tx) * K + k];
#pragma unroll
            for (int rr = 0; rr < 4; ++rr) acc[rr][cc] = fmaf(a[rr], w, acc[rr][cc]);
        }
    }
#pragma unroll
    for (int cc = 0; cc < CPT; ++cc) {
        int col = cc * 16 + tx;
        float bv = bias[col];
        float s = 0.f, q = 0.f;
#pragma unroll
        for (int rr = 0; rr < 4; ++rr) {
            acc[rr][cc] += bv;
            float v = acc[rr][cc];
            s += v; q += v * v;
        }
        scr[ty * N + col] = s;
        scr[16 * N + ty * N + col] = q;
    }
    __syncthreads();
    for (int off = 8; off > 0; off >>= 1) {
        if (ty < off) {
#pragma unroll
            for (int cc = 0; cc < CPT; ++cc) {
                int col = cc * 16 + tx;
                scr[ty * N + col] += scr[(ty + off) * N + col];
                scr[16 * N + ty * N + col] += scr[16 * N + (ty + off) * N + col];
            }
        }
        __syncthreads();
    }
#pragma unroll
    for (int cc = 0; cc < CPT; ++cc) {
        int col = cc * 16 + tx;
        float mu = scr[col] * (1.f / 64.f);
        float var = scr[16 * N + col] * (1.f / 64.f) - mu * mu;
        float sc = rsqrtf(var + 1e-5f) * g[col];
        float bb = beta[col];
#pragma unroll
        for (int rr = 0; rr < 4; ++rr) {
            float v = (acc[rr][cc] - mu) * sc + bb;
            Z[(ty * 4 + rr) * (N + 1) + col] = fmaxf(v, 0.f);
        }
    }
    __syncthreads();
}

__global__ __launch_bounds__(256) void tail_kernel(
    const float* __restrict__ yv,
    const float* wm, const float* bm, const float* gm, const float* em,
    const float* wd1, const float* bd1, const float* gd1, const float* ed1,
    const float* wd2, const float* bd2, const float* gd2, const float* ed2,
    const float* wc, const float* bc, float* __restrict__ out) {
    __shared__ float smem[14464];
    float* z1 = smem;                 // 64*129
    float* s1 = smem + 8256;          // 2*16*128
    float* z2 = smem + 8256;          // 64*65 (reuses dead s1)
    float* s2 = smem + 12416;         // 2*16*64
    float* z3 = smem;                 // 64*33 (reuses dead z1)
    float* s3 = smem + 2112;          // 2*16*32

    tail_layer<128, 256>(yv, 256, wm, bm, gm, em, z1, s1);
    tail_layer<64, 128>(z1, 129, wd1, bd1, gd1, ed1, z2, s2);
    tail_layer<32, 64>(z2, 65, wd2, bd2, gd2, ed2, z3, s3);
    for (int o = threadIdx.x; o < 640; o += 256) {
        int r = o / 10, c = o % 10;
        float s = bc[c];
#pragma unroll
        for (int k = 0; k < 32; ++k) s = fmaf(z3[r * 33 + k], wc[c * 32 + k], s);
        out[o] = s;
    }
}

// ---------------- launch ----------------

extern "C" void kernel_launch(void* const* d_in, const int* in_sizes, int n_in,
                              void* d_out, int out_size, void* d_ws, size_t ws_size,
                              hipStream_t stream) {
    (void)in_sizes; (void)n_in; (void)out_size; (void)ws_size;
    // ALL float tensors are float32 per the reference; positions is int32.
    const float* x  = (const float*)d_in[0];
    const int* pos  = (const int*)d_in[1];
    const float *w1 = (const float*)d_in[2],  *b1 = (const float*)d_in[3],
                *g1 = (const float*)d_in[4],  *e1 = (const float*)d_in[5];
    const float *w2 = (const float*)d_in[6],  *b2 = (const float*)d_in[7],
                *g2 = (const float*)d_in[8],  *e2 = (const float*)d_in[9];
    const float *w3 = (const float*)d_in[10], *b3 = (const float*)d_in[11],
                *g3 = (const float*)d_in[12], *e3 = (const float*)d_in[13];
    const float *ws1 = (const float*)d_in[14], *ws2 = (const float*)d_in[15];
    const float *wi = (const float*)d_in[16], *bi = (const float*)d_in[17],
                *gi = (const float*)d_in[18], *ei = (const float*)d_in[19];
    const float *wk = (const float*)d_in[20], *bk = (const float*)d_in[21];   // k before q!
    const float *wq = (const float*)d_in[22], *bq = (const float*)d_in[23];
    const float *wm = (const float*)d_in[24], *bm = (const float*)d_in[25],
                *gm = (const float*)d_in[26], *em = (const float*)d_in[27];
    const float *wd1 = (const float*)d_in[28], *bd1 = (const float*)d_in[29],
                *gd1 = (const float*)d_in[30], *ed1 = (const float*)d_in[31];
    const float *wd2 = (const float*)d_in[32], *bd2 = (const float*)d_in[33],
                *gd2 = (const float*)d_in[34], *ed2 = (const float*)d_in[35];
    const float *wc = (const float*)d_in[36], *bc = (const float*)d_in[37];
    float* out = (float*)d_out;

    // workspace layout (bytes), total ~26.4 MB
    char* w8 = (char*)d_ws;
    bf16*  actA  = (bf16*)(w8);                     // 11,960,320 B
    bf16*  actB  = (bf16*)(w8 + 11960320);          // 11,960,320 B
    bf16*  xb    = (bf16*)(w8 + 23920640);          //    467,200 B
    float* tab   = (float*)(w8 + 24387840);         //    435,200 B
    float* stats = (float*)(w8 + 24823040);         //      8,192 B (4 layers x 512 f32)
    float* sebuf = (float*)(w8 + 24831232);         //     65,536 B
    float* ksumb = (float*)(w8 + 24896768);         //     32,768 B
    float* attw  = (float*)(w8 + 24929536);         //  1,495,040 B
    float* yvb   = (float*)(w8 + 26424576);         //     65,536 B
    bf16*  qbuf  = actA;
    bf16*  kbuf  = actA + (size_t)BT * 128;

    zero_kernel<<<8, 256, 0, stream>>>(stats, 2048);
    cast_kernel<<<(BT * 10 + 255) / 256, 256, 0, stream>>>(x, xb, BT * 10);
    postab_kernel<<<NPOS, 256, 0, stream>>>(tab);

    // encoder L1: 10 -> 64
    gemm_kernel<64><<<dim3(365, 1), 256, 0, stream>>>(xb, 10, w1, b1, actB, 64, stats);
    bnrelu_kernel<<<BT * 64 / 256, 256, 0, stream>>>(actB, 64, stats, g1, e1, actA, nullptr, nullptr);
    // encoder L2: 64 -> 128
    gemm_kernel<128><<<dim3(365, 1), 256, 0, stream>>>(actA, 64, w2, b2, actB, 128, stats + 512);
    bnrelu_kernel<<<BT * 128 / 256, 256, 0, stream>>>(actB, 128, stats + 512, g2, e2, actA, nullptr, nullptr);
    // encoder L3: 128 -> 256
    gemm_kernel<128><<<dim3(365, 2), 256, 0, stream>>>(actA, 128, w3, b3, actB, 256, stats + 1024);
    bnrelu_kernel<<<BT * 256 / 256, 256, 0, stream>>>(actB, 256, stats + 1024, g3, e3, actA, nullptr, nullptr);
    // SE + residual
    se_kernel<<<64, 256, 0, stream>>>(actA, ws1, ws2, sebuf);
    residual_kernel<<<BT * 256 / 256, 256, 0, stream>>>(actA, sebuf, actB);
    // inconv 256 -> 256, BN/ReLU + positional add -> e (actB)
    gemm_kernel<128><<<dim3(365, 2), 256, 0, stream>>>(actB, 256, wi, bi, actA, 256, stats + 1536);
    bnrelu_kernel<<<BT * 256 / 256, 256, 0, stream>>>(actA, 256, stats + 1536, gi, ei, actB, tab, pos);
    // q,k projections from e
    gemm_kernel<128><<<dim3(365, 1), 256, 0, stream>>>(actB, 256, wq, bq, qbuf, 128, nullptr);
    gemm_kernel<128><<<dim3(365, 1), 256, 0, stream>>>(actB, 256, wk, bk, kbuf, 128, nullptr);
    // collapsed attention
    ksum_kernel<<<64, 128, 0, stream>>>(kbuf, ksumb);
    attsm_kernel<<<1024, 64, 0, stream>>>(qbuf, ksumb, attw);
    yv_kernel<<<64, 256, 0, stream>>>(actB, attw, yvb);
    // fused tail
    tail_kernel<<<1, 256, 0, stream>>>(yvb, wm, bm, gm, em, wd1, bd1, gd1, ed1,
                                       wd2, bd2, gd2, ed2, wc, bc, out);
}

// Round 4
// 617.525 us; speedup vs baseline: 1.0836x; 1.0836x over previous
//
#include <hip/hip_runtime.h>
#include <hip/hip_bf16.h>
#include <math.h>

// Shapes fixed by the reference
#define TT     365
#define BT     23360      // 64*365
#define NPOS   425

typedef __hip_bfloat16 bf16;
typedef __attribute__((ext_vector_type(8))) short s16x8;
typedef __attribute__((ext_vector_type(4))) float f32x4;

__device__ __forceinline__ float b2f(bf16 v) { return __bfloat162float(v); }
__device__ __forceinline__ bf16  f2b(float v) { return __float2bfloat16(v); }
__device__ __forceinline__ float u2f(unsigned u) { return __uint_as_float(u); }

// ---------------- fused prep: zero stats/pooled/ksum/yv, cast x, split-cast weights, pos table ---
// weight segment element offsets in whi/wlo: w2@0(8192) w3@8192(32768) wi@40960(65536)
// wq@106496(32768) wk@139264(32768); total 172032
__global__ __launch_bounds__(256) void prep_kernel(
    float* __restrict__ stats, float* __restrict__ pooled,
    float* __restrict__ ksumb, float* __restrict__ yvb,
    const float* __restrict__ x, bf16* __restrict__ xb,
    const float* __restrict__ w2, const float* __restrict__ w3, const float* __restrict__ wi,
    const float* __restrict__ wq, const float* __restrict__ wk,
    bf16* __restrict__ whi, bf16* __restrict__ wlo, float* __restrict__ tab)
{
    int i = blockIdx.x * 256 + threadIdx.x;
    if (i < 2048)   { stats[i] = 0.f; return; }  i -= 2048;
    if (i < 16384)  { pooled[i] = 0.f; return; } i -= 16384;
    if (i < 8192)   { ksumb[i] = 0.f; return; }  i -= 8192;
    if (i < 16384)  { yvb[i] = 0.f; return; }    i -= 16384;
    if (i < 233600) { xb[i] = f2b(x[i]); return; } i -= 233600;
    if (i < 172032) {
        float w;
        if      (i < 8192)   w = w2[i];
        else if (i < 40960)  w = w3[i - 8192];
        else if (i < 106496) w = wi[i - 40960];
        else if (i < 139264) w = wq[i - 106496];
        else                 w = wk[i - 139264];
        bf16 h = f2b(w);
        whi[i] = h;
        wlo[i] = f2b(w - b2f(h));
        return;
    } i -= 172032;
    if (i < 108800) {
        int c = i & 255, p = i >> 8;
        double e = (double)(2 * (c >> 1)) / 256.0;
        double ang = (double)p / pow(1000.0, e);
        tab[i] = (float)((c & 1) ? cos(ang) : sin(ang));
    }
}

// ---------------- L1 scalar GEMM (K=10): Y[M,64](bf16) = A(bf16)@W(f32)^T + b; fused BN stats ----
template<int NCOLS>
__global__ __launch_bounds__(256) void gemm_kernel(
    const bf16* __restrict__ A, int K,
    const float* __restrict__ W, const float* __restrict__ bias,
    bf16* __restrict__ Y, int ldY, float* __restrict__ stats)
{
    const int t  = threadIdx.x;
    const int tx = t & 15, ty = t >> 4;
    const int row0 = blockIdx.x * 64;
    constexpr int CPT = NCOLS / 16;
    __shared__ float As[64][17];
    __shared__ float Ws[16][NCOLS + 1];
    __shared__ float red_s[4][NCOLS];
    __shared__ float red_q[4][NCOLS];
    float acc[4][CPT];
#pragma unroll
    for (int rr = 0; rr < 4; ++rr)
#pragma unroll
        for (int cc = 0; cc < CPT; ++cc) acc[rr][cc] = 0.f;
    for (int k0 = 0; k0 < K; k0 += 16) {
#pragma unroll
        for (int i = 0; i < 4; ++i) {
            int idx = t + i * 256, r = idx >> 4, c = idx & 15, k = k0 + c;
            As[r][c] = (k < K) ? b2f(A[(size_t)(row0 + r) * K + k]) : 0.f;
        }
#pragma unroll
        for (int i = 0; i < CPT; ++i) {
            int idx = t + i * 256, c = idx >> 4, kk = idx & 15, k = k0 + kk;
            Ws[kk][c] = (k < K) ? W[(size_t)c * K + k] : 0.f;
        }
        __syncthreads();
#pragma unroll
        for (int kk = 0; kk < 16; ++kk) {
            float a[4];
#pragma unroll
            for (int rr = 0; rr < 4; ++rr) a[rr] = As[ty * 4 + rr][kk];
#pragma unroll
            for (int cc = 0; cc < CPT; ++cc) {
                float w = Ws[kk][cc * 16 + tx];
#pragma unroll
                for (int rr = 0; rr < 4; ++rr) acc[rr][cc] = fmaf(a[rr], w, acc[rr][cc]);
            }
        }
        __syncthreads();
    }
    float s_cc[CPT], q_cc[CPT];
#pragma unroll
    for (int cc = 0; cc < CPT; ++cc) { s_cc[cc] = 0.f; q_cc[cc] = 0.f; }
#pragma unroll
    for (int rr = 0; rr < 4; ++rr) {
        int row = row0 + ty * 4 + rr;
#pragma unroll
        for (int cc = 0; cc < CPT; ++cc) {
            int col = cc * 16 + tx;
            float v = acc[rr][cc] + bias[col];
            Y[(size_t)row * ldY + col] = f2b(v);
            s_cc[cc] += v; q_cc[cc] += v * v;
        }
    }
    int w = t >> 6;
#pragma unroll
    for (int cc = 0; cc < CPT; ++cc) {
        float s = s_cc[cc], q = q_cc[cc];
        s += __shfl_xor(s, 16); q += __shfl_xor(q, 16);
        s += __shfl_xor(s, 32); q += __shfl_xor(q, 32);
        if ((t & 63) < 16) { red_s[w][cc * 16 + tx] = s; red_q[w][cc * 16 + tx] = q; }
    }
    __syncthreads();
    if (t < NCOLS) {
        float s = red_s[0][t] + red_s[1][t] + red_s[2][t] + red_s[3][t];
        float q = red_q[0][t] + red_q[1][t] + red_q[2][t] + red_q[3][t];
        atomicAdd(&stats[t], s);
        atomicAdd(&stats[256 + t], q);
    }
}

// ---------------- MFMA GEMM: Y[M,ldY](bf16) = A(bf16) @ (Whi+Wlo)(bf16)^T + bias(f32) ----------
// Block = 256 threads = 4 waves; wave w covers rows [blockIdx.x*64 + w*16, +16), cols TILES*16.
// A-frag: A[m=lane&15][k=quad*8+j]; B-frag: W[n=lane&15][k=quad*8+j]; C: col=lane&15,row=quad*4+r.
template<int TILES>
__global__ __launch_bounds__(256) void mfma_gemm(
    const bf16* __restrict__ A, int K,
    const bf16* __restrict__ Whi, const bf16* __restrict__ Wlo,
    const float* __restrict__ bias,
    bf16* __restrict__ Y, int ldY, float* __restrict__ stats)
{
    __shared__ float red_s[4][TILES * 16];
    __shared__ float red_q[4][TILES * 16];
    const int t = threadIdx.x, wave = t >> 6, lane = t & 63;
    const int n16 = lane & 15, quad = lane >> 4;
    const int m0 = blockIdx.x * 64 + wave * 16;
    const int col0 = blockIdx.y * (TILES * 16);
    f32x4 acc[TILES];
    f32x4 zero = {0.f, 0.f, 0.f, 0.f};
#pragma unroll
    for (int ct = 0; ct < TILES; ++ct) acc[ct] = zero;
    const bf16* Ap = A + (size_t)(m0 + n16) * K + quad * 8;
    const size_t wbase = (size_t)(col0 + n16) * K + quad * 8;
    for (int k0 = 0; k0 < K; k0 += 32) {
        s16x8 af = *(const s16x8*)(Ap + k0);
#pragma unroll
        for (int ct = 0; ct < TILES; ++ct) {
            size_t wo = wbase + (size_t)ct * 16 * K + k0;
            s16x8 bl = *(const s16x8*)(Wlo + wo);
            s16x8 bh = *(const s16x8*)(Whi + wo);
            acc[ct] = __builtin_amdgcn_mfma_f32_16x16x32_bf16(af, bl, acc[ct], 0, 0, 0);
            acc[ct] = __builtin_amdgcn_mfma_f32_16x16x32_bf16(af, bh, acc[ct], 0, 0, 0);
        }
    }
#pragma unroll
    for (int ct = 0; ct < TILES; ++ct) {
        int col = col0 + ct * 16 + n16;
        float bv = bias[col];
        float s = 0.f, q = 0.f;
#pragma unroll
        for (int r = 0; r < 4; ++r) {
            float v = acc[ct][r] + bv;
            int row = m0 + quad * 4 + r;
            Y[(size_t)row * ldY + col] = f2b(v);
            s += v; q += v * v;
        }
        s += __shfl_xor(s, 16); q += __shfl_xor(q, 16);
        s += __shfl_xor(s, 32); q += __shfl_xor(q, 32);
        if (quad == 0) { red_s[wave][ct * 16 + n16] = s; red_q[wave][ct * 16 + n16] = q; }
    }
    if (stats) {
        __syncthreads();
        if (t < TILES * 16) {
            float s = red_s[0][t] + red_s[1][t] + red_s[2][t] + red_s[3][t];
            float q = red_q[0][t] + red_q[1][t] + red_q[2][t] + red_q[3][t];
            atomicAdd(&stats[col0 + t], s);
            atomicAdd(&stats[256 + col0 + t], q);
        }
    }
}

// ---------------- BN + ReLU (+ positional add), 8 elems/thread ----------------
__global__ __launch_bounds__(256) void bnrelu8_kernel(
    const bf16* __restrict__ Y, int N, const float* __restrict__ stats,
    const float* __restrict__ g, const float* __restrict__ beta,
    bf16* __restrict__ Out, const float* __restrict__ tab, const int* __restrict__ pos) {
    int i = (blockIdx.x * 256 + threadIdx.x) * 8;
    int col = i % N, row = i / N;
    uint4 raw = *(const uint4*)(Y + i);
    float v[8];
    v[0] = u2f(raw.x << 16); v[1] = u2f(raw.x & 0xffff0000u);
    v[2] = u2f(raw.y << 16); v[3] = u2f(raw.y & 0xffff0000u);
    v[4] = u2f(raw.z << 16); v[5] = u2f(raw.z & 0xffff0000u);
    v[6] = u2f(raw.w << 16); v[7] = u2f(raw.w & 0xffff0000u);
    const float invM = 1.f / (float)BT;
    const float* tr = tab ? (tab + pos[row] * 256 + col) : nullptr;
    bf16 tmp[8] __attribute__((aligned(16)));
#pragma unroll
    for (int j = 0; j < 8; ++j) {
        float mu  = stats[col + j] * invM;
        float var = stats[256 + col + j] * invM - mu * mu;
        float o = (v[j] - mu) * rsqrtf(var + 1e-5f) * g[col + j] + beta[col + j];
        o = fmaxf(o, 0.f);
        if (tr) o += tr[j];
        tmp[j] = f2b(o);
    }
    *(uint4*)(Out + i) = *(const uint4*)tmp;
}

// ---------------- pooled[b,f] += partial row-sum of a3 ----------------
__global__ __launch_bounds__(256) void pool_kernel(const bf16* __restrict__ a3,
                                                   float* __restrict__ pooled) {
    int b = blockIdx.x, part = blockIdx.y, f = threadIdx.x;
    int r0 = part * 46, r1 = min(r0 + 46, TT);
    const bf16* p = a3 + ((size_t)b * TT + r0) * 256 + f;
    float s = 0.f;
    for (int r = r0; r < r1; ++r, p += 256) s += b2f(*p);
    atomicAdd(&pooled[b * 256 + f], s);
}

// ---------------- SE MLP: se[b,f] = sigmoid(relu(mean@ws1^T)@ws2^T) * mean ----------------
__global__ __launch_bounds__(256) void se_mlp_kernel(const float* __restrict__ pooled,
                                                     const float* __restrict__ ws1,
                                                     const float* __restrict__ ws2,
                                                     float* __restrict__ se) {
    int b = blockIdx.x, f = threadIdx.x;
    __shared__ float pl[256];
    __shared__ float hidden[16];
    float p = pooled[b * 256 + f] * (1.f / (float)TT);
    pl[f] = p;
    __syncthreads();
    if (f < 16) {
        float h = 0.f;
        for (int k = 0; k < 256; ++k) h = fmaf(pl[k], ws1[f * 256 + k], h);
        hidden[f] = fmaxf(h, 0.f);
    }
    __syncthreads();
    float a = 0.f;
    for (int k = 0; k < 16; ++k) a = fmaf(hidden[k], ws2[f * 16 + k], a);
    a = 1.f / (1.f + expf(-a));
    se[b * 256 + f] = a * p;
}

// ---------------- residual: out = a3 + se[b,:], 8 elems/thread ----------------
__global__ __launch_bounds__(256) void residual8_kernel(const bf16* __restrict__ a3,
                                                        const float* __restrict__ se,
                                                        bf16* __restrict__ out) {
    int i = (blockIdx.x * 256 + threadIdx.x) * 8;
    int col = i & 255, row = i >> 8;
    int b = row / TT;
    uint4 raw = *(const uint4*)(a3 + i);
    float v[8];
    v[0] = u2f(raw.x << 16); v[1] = u2f(raw.x & 0xffff0000u);
    v[2] = u2f(raw.y << 16); v[3] = u2f(raw.y & 0xffff0000u);
    v[4] = u2f(raw.z << 16); v[5] = u2f(raw.z & 0xffff0000u);
    v[6] = u2f(raw.w << 16); v[7] = u2f(raw.w & 0xffff0000u);
    const float* sp = se + b * 256 + col;
    bf16 tmp[8] __attribute__((aligned(16)));
#pragma unroll
    for (int j = 0; j < 8; ++j) tmp[j] = f2b(v[j] + sp[j]);
    *(uint4*)(out + i) = *(const uint4*)tmp;
}

// ---------------- ksum partial ----------------
__global__ __launch_bounds__(128) void ksum_kernel(const bf16* __restrict__ k,
                                                   float* __restrict__ ksum) {
    int b = blockIdx.x, part = blockIdx.y, f = threadIdx.x;
    int r0 = part * 92, r1 = min(r0 + 92, TT);
    const bf16* p = k + ((size_t)b * TT + r0) * 128 + f;
    float s = 0.f;
    for (int r = r0; r < r1; ++r, p += 128) s += b2f(*p);
    atomicAdd(&ksum[b * 128 + f], s);
}

// ---------------- per-(b,h) mean-score softmax over T; one wave each ----------------
__global__ __launch_bounds__(64) void attsm_kernel(const bf16* __restrict__ q,
                                                   const float* __restrict__ ksum,
                                                   float* __restrict__ attw) {
    int bh = blockIdx.x, b = bh >> 4, h = bh & 15;
    int lane = threadIdx.x;
    float kk[8];
#pragma unroll
    for (int d = 0; d < 8; ++d) kk[d] = ksum[b * 128 + h * 8 + d];
    const float scale = 1.f / (sqrtf(8.f) * (float)TT);
    float sv[6];
    float m = -1e30f;
#pragma unroll
    for (int i = 0; i < 6; ++i) {
        int tt = lane + i * 64;
        float v = -1e30f;
        if (tt < TT) {
            const uint4 raw = *(const uint4*)(q + (size_t)(b * TT + tt) * 128 + h * 8);
            float qv[8];
            qv[0] = u2f(raw.x << 16); qv[1] = u2f(raw.x & 0xffff0000u);
            qv[2] = u2f(raw.y << 16); qv[3] = u2f(raw.y & 0xffff0000u);
            qv[4] = u2f(raw.z << 16); qv[5] = u2f(raw.z & 0xffff0000u);
            qv[6] = u2f(raw.w << 16); qv[7] = u2f(raw.w & 0xffff0000u);
            float dot = 0.f;
#pragma unroll
            for (int d = 0; d < 8; ++d) dot = fmaf(qv[d], kk[d], dot);
            v = dot * scale;
        }
        sv[i] = v;
        m = fmaxf(m, v);
    }
    for (int off = 32; off > 0; off >>= 1) m = fmaxf(m, __shfl_xor(m, off));
    float sum = 0.f;
#pragma unroll
    for (int i = 0; i < 6; ++i) {
        float e = (sv[i] > -1e29f) ? expf(sv[i] - m) : 0.f;
        sv[i] = e; sum += e;
    }
    for (int off = 32; off > 0; off >>= 1) sum += __shfl_xor(sum, off);
    float inv = 1.f / sum;
#pragma unroll
    for (int i = 0; i < 6; ++i) {
        int tt = lane + i * 64;
        if (tt < TT) attw[(size_t)bh * TT + tt] = sv[i] * inv;
    }
}

// ---------------- yv[b,f] += partial_t attw[b,f/16,t] * e[b,t,f] ----------------
__global__ __launch_bounds__(256) void yv_kernel(const bf16* __restrict__ e,
                                                 const float* __restrict__ attw,
                                                 float* __restrict__ yv) {
    int b = blockIdx.x, part = blockIdx.y, f = threadIdx.x;
    int h = f >> 4;
    int r0 = part * 46, r1 = min(r0 + 46, TT);
    const bf16* p = e + ((size_t)b * TT + r0) * 256 + f;
    const float* aw = attw + (size_t)(b * 16 + h) * TT;
    float s = 0.f;
    for (int r = r0; r < r1; ++r, p += 256) s = fmaf(aw[r], b2f(*p), s);
    atomicAdd(&yv[b * 256 + f], s);
}

// ---------------- fused tail: 3 BN-linear layers + classifier, one block, W staged in LDS -------
template<int N, int K>
__device__ void tail_layer(const float* __restrict__ X, int ldx,
                           const float* __restrict__ W, const float* __restrict__ bias,
                           const float* __restrict__ g, const float* __restrict__ beta,
                           float* Z, float* scr, float* Wl) {
    const int t = threadIdx.x;
    const int tx = t & 15, ty = t >> 4;
    constexpr int CPT = N / 16;
    float acc[4][CPT];
#pragma unroll
    for (int rr = 0; rr < 4; ++rr)
#pragma unroll
        for (int cc = 0; cc < CPT; ++cc) acc[rr][cc] = 0.f;
    for (int k0 = 0; k0 < K; k0 += 16) {
        // stage W[*, k0..k0+16) into Wl[kk][n], coalesced
        for (int i = t; i < N * 16; i += 256) {
            int n = i >> 4, kk = i & 15;
            Wl[kk * (N + 1) + n] = W[(size_t)n * K + k0 + kk];
        }
        __syncthreads();
#pragma unroll
        for (int kk = 0; kk < 16; ++kk) {
            float a[4];
#pragma unroll
            for (int rr = 0; rr < 4; ++rr) a[rr] = X[(ty * 4 + rr) * ldx + k0 + kk];
#pragma unroll
            for (int cc = 0; cc < CPT; ++cc) {
                float w = Wl[kk * (N + 1) + cc * 16 + tx];
#pragma unroll
                for (int rr = 0; rr < 4; ++rr) acc[rr][cc] = fmaf(a[rr], w, acc[rr][cc]);
            }
        }
        __syncthreads();
    }
#pragma unroll
    for (int cc = 0; cc < CPT; ++cc) {
        int col = cc * 16 + tx;
        float bv = bias[col];
        float s = 0.f, q = 0.f;
#pragma unroll
        for (int rr = 0; rr < 4; ++rr) {
            acc[rr][cc] += bv;
            float v = acc[rr][cc];
            s += v; q += v * v;
        }
        scr[ty * N + col] = s;
        scr[16 * N + ty * N + col] = q;
    }
    __syncthreads();
    for (int off = 8; off > 0; off >>= 1) {
        if (ty < off) {
#pragma unroll
            for (int cc = 0; cc < CPT; ++cc) {
                int col = cc * 16 + tx;
                scr[ty * N + col] += scr[(ty + off) * N + col];
                scr[16 * N + ty * N + col] += scr[16 * N + (ty + off) * N + col];
            }
        }
        __syncthreads();
    }
#pragma unroll
    for (int cc = 0; cc < CPT; ++cc) {
        int col = cc * 16 + tx;
        float mu = scr[col] * (1.f / 64.f);
        float var = scr[16 * N + col] * (1.f / 64.f) - mu * mu;
        float sc = rsqrtf(var + 1e-5f) * g[col];
        float bb = beta[col];
#pragma unroll
        for (int rr = 0; rr < 4; ++rr) {
            float v = (acc[rr][cc] - mu) * sc + bb;
            Z[(ty * 4 + rr) * (N + 1) + col] = fmaxf(v, 0.f);
        }
    }
    __syncthreads();
}

__global__ __launch_bounds__(256) void tail_kernel(
    const float* __restrict__ yv,
    const float* wm, const float* bm, const float* gm, const float* em,
    const float* wd1, const float* bd1, const float* gd1, const float* ed1,
    const float* wd2, const float* bd2, const float* gd2, const float* ed2,
    const float* wc, const float* bc, float* __restrict__ out) {
    __shared__ float smem[15504];
    // L1: z1@0(8256) s1@8256(4096) Wl1@12352(2064)
    // L2: X=z1@0, z2@8256(4160) s2@12416(2048) Wl2@14464(1040)
    // L3: X=z2@8256, z3@0(2112) s3@2112(1024) Wl3@3136(528)
    tail_layer<128, 256>(yv, 256, wm, bm, gm, em, smem, smem + 8256, smem + 12352);
    tail_layer<64, 128>(smem, 129, wd1, bd1, gd1, ed1, smem + 8256, smem + 12416, smem + 14464);
    tail_layer<32, 64>(smem + 8256, 65, wd2, bd2, gd2, ed2, smem, smem + 2112, smem + 3136);
    for (int o = threadIdx.x; o < 640; o += 256) {
        int r = o / 10, c = o % 10;
        float s = bc[c];
#pragma unroll
        for (int k = 0; k < 32; ++k) s = fmaf(smem[r * 33 + k], wc[c * 32 + k], s);
        out[o] = s;
    }
}

// ---------------- launch ----------------

extern "C" void kernel_launch(void* const* d_in, const int* in_sizes, int n_in,
                              void* d_out, int out_size, void* d_ws, size_t ws_size,
                              hipStream_t stream) {
    (void)in_sizes; (void)n_in; (void)out_size; (void)ws_size;
    const float* x  = (const float*)d_in[0];
    const int* pos  = (const int*)d_in[1];
    const float *w1 = (const float*)d_in[2],  *b1 = (const float*)d_in[3],
                *g1 = (const float*)d_in[4],  *e1 = (const float*)d_in[5];
    const float *w2 = (const float*)d_in[6],  *b2 = (const float*)d_in[7],
                *g2 = (const float*)d_in[8],  *e2 = (const float*)d_in[9];
    const float *w3 = (const float*)d_in[10], *b3 = (const float*)d_in[11],
                *g3 = (const float*)d_in[12], *e3 = (const float*)d_in[13];
    const float *ws1 = (const float*)d_in[14], *ws2 = (const float*)d_in[15];
    const float *wi = (const float*)d_in[16], *bi = (const float*)d_in[17],
                *gi = (const float*)d_in[18], *ei = (const float*)d_in[19];
    const float *wk = (const float*)d_in[20], *bk = (const float*)d_in[21];   // k before q!
    const float *wq = (const float*)d_in[22], *bq = (const float*)d_in[23];
    const float *wm = (const float*)d_in[24], *bm = (const float*)d_in[25],
                *gm = (const float*)d_in[26], *em = (const float*)d_in[27];
    const float *wd1 = (const float*)d_in[28], *bd1 = (const float*)d_in[29],
                *gd1 = (const float*)d_in[30], *ed1 = (const float*)d_in[31];
    const float *wd2 = (const float*)d_in[32], *bd2 = (const float*)d_in[33],
                *gd2 = (const float*)d_in[34], *ed2 = (const float*)d_in[35];
    const float *wc = (const float*)d_in[36], *bc = (const float*)d_in[37];
    float* out = (float*)d_out;

    // workspace layout (bytes), total ~27.25 MB
    char* w8 = (char*)d_ws;
    bf16*  actA   = (bf16*)(w8);                    // 11,960,320
    bf16*  actB   = (bf16*)(w8 + 11960320);         // 11,960,320
    bf16*  xb     = (bf16*)(w8 + 23920640);         //    467,200
    bf16*  whi    = (bf16*)(w8 + 24387840);         //    344,064
    bf16*  wlo    = (bf16*)(w8 + 24731904);         //    344,064
    float* tab    = (float*)(w8 + 25075968);        //    435,200
    float* stats  = (float*)(w8 + 25511168);        //      8,192
    float* pooled = (float*)(w8 + 25519360);        //     65,536
    float* sebuf  = (float*)(w8 + 25584896);        //     65,536
    float* ksumb  = (float*)(w8 + 25650432);        //     32,768
    float* attw   = (float*)(w8 + 25683200);        //  1,495,040
    float* yvb    = (float*)(w8 + 27178240);        //     65,536
    bf16*  qbuf   = actA;
    bf16*  kbuf   = actA + (size_t)BT * 128;

    prep_kernel<<<2178, 256, 0, stream>>>(stats, pooled, ksumb, yvb, x, xb,
                                          w2, w3, wi, wq, wk, whi, wlo, tab);
    // encoder L1: 10 -> 64 (scalar path, K=10)
    gemm_kernel<64><<<365, 256, 0, stream>>>(xb, 10, w1, b1, actB, 64, stats);
    bnrelu8_kernel<<<BT * 64 / 2048, 256, 0, stream>>>(actB, 64, stats, g1, e1, actA, nullptr, nullptr);
    // encoder L2: 64 -> 128 (MFMA)
    mfma_gemm<8><<<dim3(365, 1), 256, 0, stream>>>(actA, 64, whi, wlo, b2, actB, 128, stats + 512);
    bnrelu8_kernel<<<BT * 128 / 2048, 256, 0, stream>>>(actB, 128, stats + 512, g2, e2, actA, nullptr, nullptr);
    // encoder L3: 128 -> 256 (MFMA)
    mfma_gemm<16><<<dim3(365, 1), 256, 0, stream>>>(actA, 128, whi + 8192, wlo + 8192, b3, actB, 256, stats + 1024);
    bnrelu8_kernel<<<BT * 256 / 2048, 256, 0, stream>>>(actB, 256, stats + 1024, g3, e3, actA, nullptr, nullptr);
    // SE + residual
    pool_kernel<<<dim3(64, 8), 256, 0, stream>>>(actA, pooled);
    se_mlp_kernel<<<64, 256, 0, stream>>>(pooled, ws1, ws2, sebuf);
    residual8_kernel<<<BT * 256 / 2048, 256, 0, stream>>>(actA, sebuf, actB);
    // inconv 256 -> 256 (MFMA), BN/ReLU + positional add -> e (actB)
    mfma_gemm<16><<<dim3(365, 1), 256, 0, stream>>>(actB, 256, whi + 40960, wlo + 40960, bi, actA, 256, stats + 1536);
    bnrelu8_kernel<<<BT * 256 / 2048, 256, 0, stream>>>(actA, 256, stats + 1536, gi, ei, actB, tab, pos);
    // q,k projections (MFMA)
    mfma_gemm<8><<<dim3(365, 1), 256, 0, stream>>>(actB, 256, whi + 106496, wlo + 106496, bq, qbuf, 128, nullptr);
    mfma_gemm<8><<<dim3(365, 1), 256, 0, stream>>>(actB, 256, whi + 139264, wlo + 139264, bk, kbuf, 128, nullptr);
    // collapsed attention
    ksum_kernel<<<dim3(64, 4), 128, 0, stream>>>(kbuf, ksumb);
    attsm_kernel<<<1024, 64, 0, stream>>>(qbuf, ksumb, attw);
    yv_kernel<<<dim3(64, 8), 256, 0, stream>>>(actB, attw, yvb);
    // fused tail
    tail_kernel<<<1, 256, 0, stream>>>(yvb, wm, bm, gm, em, wd1, bd1, gd1, ed1,
                                       wd2, bd2, gd2, ed2, wc, bc, out);
}